// Round 2
// baseline (282.996 us; speedup 1.0000x reference)
//
#include <hip/hip_runtime.h>

// Problem constants (fixed by the reference):
//   V=100000, D=128, W=5 (ctx cols = 10), N=5 (neg), COLS=22, B = in_sizes[0]/22
constexpr int W2   = 10;
constexpr int NNEG = 5;
constexpr int COLS = 22;
constexpr int NBLOCKS = 2048;
constexpr int THREADS = 256;                       // 4 waves/block
constexpr int WAVES_TOTAL = NBLOCKS * (THREADS / 64);
constexpr int ROWS_PER_SWEEP = WAVES_TOTAL * 4;    // 4 rows per wave iteration

// Layout: 16 lanes per row (lane owns dims [t*8, t*8+8)), 4 rows per wave.
__global__ __launch_bounds__(THREADS) void sg_loss_kernel(
    const int*   __restrict__ data,
    const float* __restrict__ gW,      // (V+1, 128)
    const float* __restrict__ sW,      // (3V, 128)
    const float* __restrict__ cw,      // (10, 128)
    int B,
    float* __restrict__ partials)      // 2 floats per block
{
    __shared__ float cwl[W2 * 128];    // 5 KB
    __shared__ float sp[THREADS / 64], sn[THREADS / 64];
    for (int i = threadIdx.x; i < W2 * 128; i += THREADS) cwl[i] = cw[i];
    __syncthreads();

    const int lane     = threadIdx.x & 63;
    const int t        = lane & 15;        // lane within 16-lane row group
    const int baseLane = lane & ~15;       // first lane of this group (wave-relative)
    const int g        = (lane >> 4) & 3;  // row group 0..3
    const int wib      = threadIdx.x >> 6;
    const int wgid     = blockIdx.x * (THREADS >> 6) + wib;

    const float4* cwl4 = reinterpret_cast<const float4*>(cwl);

    float acc = 0.f;  // lane t==0: pos terms; lanes t=1..5: neg terms; t>=6: 0

    for (int r4 = wgid * 4; r4 < B; r4 += ROWS_PER_SWEEP) {
        const int r = r4 + g;
        const int* __restrict__ row = data + (long long)r * COLS;
        int i0 = row[t];                        // cols 0..15
        int i1 = (t < 6) ? row[16 + t] : 0;     // cols 16..21 (t>=6 -> 0)

        // ctx_feats slice: 8 dims per lane
        float4 cf0 = {0, 0, 0, 0}, cf1 = {0, 0, 0, 0};
#pragma unroll
        for (int j = 0; j < W2; ++j) {
            int idx = __shfl(i0, baseLane + j);
            const float4* e = reinterpret_cast<const float4*>(
                gW + (long long)idx * 128 + t * 8);
            float4 e0 = e[0], e1 = e[1];
            float4 w0 = cwl4[j * 32 + t * 2], w1 = cwl4[j * 32 + t * 2 + 1];
            cf0.x += e0.x * w0.x; cf0.y += e0.y * w0.y;
            cf0.z += e0.z * w0.z; cf0.w += e0.w * w0.w;
            cf1.x += e1.x * w1.x; cf1.y += e1.y * w1.y;
            cf1.z += e1.z * w1.z; cf1.w += e1.w * w1.w;
        }

        // 6 inner products: dots[0]=pos (col 11), dots[1..5]=neg n (cols 12..16)
        float dots[6];
#pragma unroll
        for (int k = 0; k < 6; ++k) {
            int idx = (k < 5) ? __shfl(i0, baseLane + 11 + k)
                              : __shfl(i1, baseLane);        // col 16 = i1 slot 0
            const float4* e = reinterpret_cast<const float4*>(
                sW + (long long)idx * 128 + t * 8);
            float4 e0 = e[0], e1 = e[1];
            float d = e0.x * cf0.x + e0.y * cf0.y + e0.z * cf0.z + e0.w * cf0.w
                    + e1.x * cf1.x + e1.y * cf1.y + e1.z * cf1.z + e1.w * cf1.w;
            dots[k] = d;
        }

        // 4-step butterfly within the 16-lane group (all lanes get full sums)
#pragma unroll
        for (int s = 1; s < 16; s <<= 1) {
#pragma unroll
            for (int k = 0; k < 6; ++k)
                dots[k] += __shfl_xor(dots[k], s);
        }

        // Lane t selects its dot: t==0 -> pos, t in 1..5 -> neg t-1, t>=6 -> dead.
        float x = dots[0];
        x = (t == 1) ? dots[1] : x;
        x = (t == 2) ? dots[2] : x;
        x = (t == 3) ? dots[3] : x;
        x = (t == 4) ? dots[4] : x;
        x = (t == 5) ? dots[5] : x;
        float c = fminf(fmaxf(x, -10.f), 10.f);
        float y = (t == 0) ? -c : c;             // pos: softplus(-clip); neg: softplus(+clip)
        float m = (t == 0) ? 1.f : (float)i1;    // mask (cols 17..21 = own i1 for t=1..5; 0 for t>=6)
        acc += m * __logf(1.f + __expf(y));
    }

    // Split into pos/neg and reduce across the wave
    float ap = (t == 0) ? acc : 0.f;
    float an = (t == 0) ? 0.f : acc;
#pragma unroll
    for (int s = 1; s < 64; s <<= 1) {
        ap += __shfl_xor(ap, s);
        an += __shfl_xor(an, s);
    }
    if (lane == 0) { sp[wib] = ap; sn[wib] = an; }
    __syncthreads();
    if (threadIdx.x == 0) {
        float tp = 0.f, tn = 0.f;
#pragma unroll
        for (int w = 0; w < THREADS / 64; ++w) { tp += sp[w]; tn += sn[w]; }
        partials[2 * blockIdx.x]     = tp;
        partials[2 * blockIdx.x + 1] = tn;
    }
}

// Deterministic final reduction: fixed traversal order, single block.
__global__ __launch_bounds__(256) void reduce_kernel(
    const float* __restrict__ partials, int nblocks, float* __restrict__ out)
{
    float tp = 0.f, tn = 0.f;
    for (int i = threadIdx.x; i < nblocks; i += 256) {
        tp += partials[2 * i];
        tn += partials[2 * i + 1];
    }
    __shared__ float sp[256], sn[256];
    sp[threadIdx.x] = tp; sn[threadIdx.x] = tn;
    __syncthreads();
    for (int s = 128; s > 0; s >>= 1) {
        if (threadIdx.x < s) {
            sp[threadIdx.x] += sp[threadIdx.x + s];
            sn[threadIdx.x] += sn[threadIdx.x + s];
        }
        __syncthreads();
    }
    if (threadIdx.x == 0) { out[0] = sp[0]; out[1] = sn[0]; }
}

extern "C" void kernel_launch(void* const* d_in, const int* in_sizes, int n_in,
                              void* d_out, int out_size, void* d_ws, size_t ws_size,
                              hipStream_t stream) {
    const int*   data       = (const int*)  d_in[0];
    const float* global_W   = (const float*)d_in[1];
    const float* sense_W    = (const float*)d_in[2];
    const float* ctx_weight = (const float*)d_in[3];
    // d_in[4] = window (5), d_in[5] = negative (5) — fixed, baked into constants.

    const int B = in_sizes[0] / COLS;     // 131072
    float* partials = (float*)d_ws;       // 2*NBLOCKS floats = 16 KB
    float* out      = (float*)d_out;      // {pos_loss, neg_loss}

    sg_loss_kernel<<<NBLOCKS, THREADS, 0, stream>>>(
        data, global_W, sense_W, ctx_weight, B, partials);
    reduce_kernel<<<1, 256, 0, stream>>>(partials, NBLOCKS, out);
}

// Round 3
// 131.173 us; speedup vs baseline: 2.1574x; 2.1574x over previous
//
#include <hip/hip_runtime.h>

// Problem constants (fixed by the reference):
//   V=100000, D=128, W=5 (ctx cols = 10), N=5 (neg), COLS=22, B = in_sizes[0]/22
// Row layout of data: [0..9]=ctx, 10=center, 11=pos, 12..16=neg, 17..21=mask
constexpr int W2   = 10;
constexpr int NNEG = 5;
constexpr int COLS = 22;
constexpr int NBLOCKS = 2048;
constexpr int THREADS = 256;                 // 4 waves/block
constexpr int WAVES_TOTAL = NBLOCKS * (THREADS / 64);

// 64 lanes per row; lane owns dims {2*lane, 2*lane+1} (float2).
// One row per wave-iteration -> narrow in-flight row window -> L2-resident
// gather footprint per XCD stays ~4MB -> ~50% L2 hit (round-1 evidence).
__global__ __launch_bounds__(THREADS) void sg_loss_kernel(
    const int*   __restrict__ data,
    const float* __restrict__ gW,      // (V+1, 128)
    const float* __restrict__ sW,      // (3V, 128)
    const float* __restrict__ cw,      // (10, 128)
    int B,
    float* __restrict__ partials)      // 2 floats per block
{
    const int lane = threadIdx.x & 63;
    const int wib  = threadIdx.x >> 6;
    const int wgid = blockIdx.x * (THREADS >> 6) + wib;
    const int t    = lane & 15;

    const float2* __restrict__ gW2 = reinterpret_cast<const float2*>(gW);
    const float2* __restrict__ sW2 = reinterpret_cast<const float2*>(sW);

    // ctx_weight slice in VGPRs: 10 x float2 = 20 VGPR
    float2 cwv[W2];
#pragma unroll
    for (int j = 0; j < W2; ++j)
        cwv[j] = reinterpret_cast<const float2*>(cw)[j * 64 + lane];

    float accp = 0.f, accn = 0.f;

    for (int r = wgid; r < B; r += WAVES_TOTAL) {
        const int* __restrict__ row = data + (long long)r * COLS;
        int v = (lane < COLS) ? row[lane] : 0;

        // ---- issue all gathers up front (max memory-level parallelism) ----
        float2 ec[W2];
#pragma unroll
        for (int j = 0; j < W2; ++j) {
            int idx = __shfl(v, j);
            ec[j] = gW2[(long long)idx * 64 + lane];
        }
        int pidx = __shfl(v, 11);
        float2 ep = sW2[(long long)pidx * 64 + lane];

        float2 en[NNEG];
#pragma unroll
        for (int n = 0; n < NNEG; ++n) {
            int mn  = __shfl(v, 17 + n);           // mask (wave-uniform)
            int idx = __shfl(v, 12 + n);
            en[n] = make_float2(0.f, 0.f);
            if (__builtin_amdgcn_readfirstlane(mn)) // scalar branch: skip gather if masked
                en[n] = sW2[(long long)idx * 64 + lane];
        }

        // ---- compute ----
        float cfx = 0.f, cfy = 0.f;
#pragma unroll
        for (int j = 0; j < W2; ++j) {
            cfx += ec[j].x * cwv[j].x;
            cfy += ec[j].y * cwv[j].y;
        }

        float dots[1 + NNEG];
        dots[0] = ep.x * cfx + ep.y * cfy;
#pragma unroll
        for (int n = 0; n < NNEG; ++n)
            dots[1 + n] = en[n].x * cfx + en[n].y * cfy;

        // 4 xor-steps within 16-lane groups on the 6-vector
#pragma unroll
        for (int s = 1; s < 16; s <<= 1) {
#pragma unroll
            for (int k = 0; k < 1 + NNEG; ++k)
                dots[k] += __shfl_xor(dots[k], s);
        }
        // per-lane select, then 2 cross-group steps on one scalar
        float x = dots[0];
        x = (t == 1) ? dots[1] : x;
        x = (t == 2) ? dots[2] : x;
        x = (t == 3) ? dots[3] : x;
        x = (t == 4) ? dots[4] : x;
        x = (t == 5) ? dots[5] : x;
        x += __shfl_xor(x, 16);
        x += __shfl_xor(x, 32);

        // lanes 0..5 hold full dots[t]; single softplus chain per row
        float c = fminf(fmaxf(x, -10.f), 10.f);
        float y = (t == 0) ? -c : c;               // pos: softplus(-c); neg: softplus(+c)
        float sp = __logf(1.f + __expf(y));
        float m  = (float)__shfl(v, 16 + t);       // cols 17..21 for t=1..5
        accp += (lane == 0) ? sp : 0.f;
        accn += (lane >= 1 && lane < 6) ? m * sp : 0.f;
    }

    // wave reduce (2 values), then block reduce
    #pragma unroll
    for (int s = 1; s < 64; s <<= 1) {
        accp += __shfl_xor(accp, s);
        accn += __shfl_xor(accn, s);
    }
    __shared__ float sp_[THREADS / 64], sn_[THREADS / 64];
    if (lane == 0) { sp_[wib] = accp; sn_[wib] = accn; }
    __syncthreads();
    if (threadIdx.x == 0) {
        float tp = 0.f, tn = 0.f;
#pragma unroll
        for (int w = 0; w < THREADS / 64; ++w) { tp += sp_[w]; tn += sn_[w]; }
        partials[2 * blockIdx.x]     = tp;
        partials[2 * blockIdx.x + 1] = tn;
    }
}

// Deterministic final reduction: fixed traversal order, single block.
__global__ __launch_bounds__(256) void reduce_kernel(
    const float* __restrict__ partials, int nblocks, float* __restrict__ out)
{
    float tp = 0.f, tn = 0.f;
    for (int i = threadIdx.x; i < nblocks; i += 256) {
        tp += partials[2 * i];
        tn += partials[2 * i + 1];
    }
    __shared__ float sp[256], sn[256];
    sp[threadIdx.x] = tp; sn[threadIdx.x] = tn;
    __syncthreads();
    for (int s = 128; s > 0; s >>= 1) {
        if (threadIdx.x < s) {
            sp[threadIdx.x] += sp[threadIdx.x + s];
            sn[threadIdx.x] += sn[threadIdx.x + s];
        }
        __syncthreads();
    }
    if (threadIdx.x == 0) { out[0] = sp[0]; out[1] = sn[0]; }
}

extern "C" void kernel_launch(void* const* d_in, const int* in_sizes, int n_in,
                              void* d_out, int out_size, void* d_ws, size_t ws_size,
                              hipStream_t stream) {
    const int*   data       = (const int*)  d_in[0];
    const float* global_W   = (const float*)d_in[1];
    const float* sense_W    = (const float*)d_in[2];
    const float* ctx_weight = (const float*)d_in[3];
    // d_in[4] = window (5), d_in[5] = negative (5) — fixed, baked into constants.

    const int B = in_sizes[0] / COLS;     // 131072
    float* partials = (float*)d_ws;       // 2*NBLOCKS floats = 16 KB
    float* out      = (float*)d_out;      // {pos_loss, neg_loss}

    sg_loss_kernel<<<NBLOCKS, THREADS, 0, stream>>>(
        data, global_W, sense_W, ctx_weight, B, partials);
    reduce_kernel<<<1, 256, 0, stream>>>(partials, NBLOCKS, out);
}

// Round 4
// 130.438 us; speedup vs baseline: 2.1696x; 1.0056x over previous
//
#include <hip/hip_runtime.h>

// Problem constants (fixed by the reference):
//   V=100000, D=128, W=5 (ctx cols = 10), N=5 (neg), COLS=22, B = in_sizes[0]/22
// Row layout of data: [0..9]=ctx, 10=center, 11=pos, 12..16=neg, 17..21=mask
constexpr int W2   = 10;
constexpr int NNEG = 5;
constexpr int COLS = 22;
constexpr int NBLOCKS = 2048;
constexpr int THREADS = 256;                 // 4 waves/block
constexpr int WAVES_TOTAL = NBLOCKS * (THREADS / 64);

// x + rotated(x) within 16-lane DPP rows (VALU, no LDS pipe).
template <int CTRL>
__device__ __forceinline__ float dpp_radd(float x) {
    int s = __builtin_amdgcn_update_dpp(0, __builtin_bit_cast(int, x),
                                        CTRL, 0xF, 0xF, false);
    return x + __builtin_bit_cast(float, s);
}

__global__ __launch_bounds__(THREADS) void sg_loss_kernel(
    const int*   __restrict__ data,
    const float* __restrict__ gW,      // (V+1, 128)
    const float* __restrict__ sW,      // (3V, 128)
    const float* __restrict__ cw,      // (10, 128)
    int B,
    float* __restrict__ partials)      // 2 floats per block
{
    const int lane = threadIdx.x & 63;
    const int wib  = threadIdx.x >> 6;
    const int t    = lane & 15;
    const int wgid = blockIdx.x * (THREADS >> 6) + wib;

    const float2* __restrict__ gW2 = reinterpret_cast<const float2*>(gW);
    const float2* __restrict__ sW2 = reinterpret_cast<const float2*>(sW);

    // ctx_weight slice in VGPRs: 10 x float2 = 20 VGPR
    float2 cwv[W2];
#pragma unroll
    for (int j = 0; j < W2; ++j)
        cwv[j] = reinterpret_cast<const float2*>(cw)[j * 64 + lane];

    float accp = 0.f, accn = 0.f;

    int r = __builtin_amdgcn_readfirstlane(wgid);

    // Prologue: fetch row r's 22 ints, lane-distributed (one vector load).
    int vidx = 0;
    {
        const int* row = data + (long long)r * COLS;
        if (lane < COLS) vidx = row[lane];
    }

    for (; r < B; ) {
        const int rn = r + WAVES_TOTAL;

        // Move indices to SGPRs: 22 v_readlane off one register.
        int id[COLS];
#pragma unroll
        for (int j = 0; j < COLS; ++j)
            id[j] = __builtin_amdgcn_readlane(vidx, j);

        // ---- issue all gathers (SGPR base + lane offset) ----
        float2 ec[W2];
#pragma unroll
        for (int j = 0; j < W2; ++j)
            ec[j] = gW2[(long long)id[j] * 64 + lane];

        float2 ep = sW2[(long long)id[11] * 64 + lane];

        float2 en[NNEG];
#pragma unroll
        for (int n = 0; n < NNEG; ++n) {
            en[n] = make_float2(0.f, 0.f);
            if (id[17 + n])                      // scalar branch: skip masked gather
                en[n] = sW2[(long long)id[12 + n] * 64 + lane];
        }

        // ---- prefetch next row's indices (consumed next iteration) ----
        if (rn < B) {
            const int* row = data + (long long)rn * COLS;
            vidx = (lane < COLS) ? row[lane] : 0;
        }

        // ---- compute ----
        float cfx = 0.f, cfy = 0.f;
#pragma unroll
        for (int j = 0; j < W2; ++j) {
            cfx += ec[j].x * cwv[j].x;
            cfy += ec[j].y * cwv[j].y;
        }

        float dots[1 + NNEG];
        dots[0] = ep.x * cfx + ep.y * cfy;
#pragma unroll
        for (int n = 0; n < NNEG; ++n)
            dots[1 + n] = en[n].x * cfx + en[n].y * cfy;

        // Within-16 reduction on the VALU via DPP row rotations.
#pragma unroll
        for (int k = 0; k < 1 + NNEG; ++k) {
            dots[k] = dpp_radd<0x128>(dots[k]);  // row_ror:8
            dots[k] = dpp_radd<0x124>(dots[k]);  // row_ror:4
            dots[k] = dpp_radd<0x122>(dots[k]);  // row_ror:2
            dots[k] = dpp_radd<0x121>(dots[k]);  // row_ror:1
        }

        // Per-lane select of its dot, then 2 cross-group steps.
        float x = dots[0];
        x = (t == 1) ? dots[1] : x;
        x = (t == 2) ? dots[2] : x;
        x = (t == 3) ? dots[3] : x;
        x = (t == 4) ? dots[4] : x;
        x = (t == 5) ? dots[5] : x;
        x += __shfl_xor(x, 16);
        x += __shfl_xor(x, 32);

        // lanes with t==0..5 now hold the full dot; one softplus chain per row.
        float c  = fminf(fmaxf(x, -10.f), 10.f);
        float y  = (t == 0) ? -c : c;            // pos: softplus(-c); neg: softplus(+c)
        float sv = __logf(1.f + __expf(y));
        float m  = 1.f;
        m = (t == 1) ? (float)id[17] : m;
        m = (t == 2) ? (float)id[18] : m;
        m = (t == 3) ? (float)id[19] : m;
        m = (t == 4) ? (float)id[20] : m;
        m = (t == 5) ? (float)id[21] : m;
        accp += (lane == 0) ? sv : 0.f;
        accn += (lane >= 1 && lane < 6) ? m * sv : 0.f;

        r = rn;
    }

    // wave reduce (2 values), then block reduce
#pragma unroll
    for (int s = 1; s < 64; s <<= 1) {
        accp += __shfl_xor(accp, s);
        accn += __shfl_xor(accn, s);
    }
    __shared__ float sp_[THREADS / 64], sn_[THREADS / 64];
    if (lane == 0) { sp_[wib] = accp; sn_[wib] = accn; }
    __syncthreads();
    if (threadIdx.x == 0) {
        float tp = 0.f, tn = 0.f;
#pragma unroll
        for (int w = 0; w < THREADS / 64; ++w) { tp += sp_[w]; tn += sn_[w]; }
        partials[2 * blockIdx.x]     = tp;
        partials[2 * blockIdx.x + 1] = tn;
    }
}

// Deterministic final reduction: fixed traversal order, single block.
__global__ __launch_bounds__(256) void reduce_kernel(
    const float* __restrict__ partials, int nblocks, float* __restrict__ out)
{
    float tp = 0.f, tn = 0.f;
    for (int i = threadIdx.x; i < nblocks; i += 256) {
        tp += partials[2 * i];
        tn += partials[2 * i + 1];
    }
    __shared__ float sp[256], sn[256];
    sp[threadIdx.x] = tp; sn[threadIdx.x] = tn;
    __syncthreads();
    for (int s = 128; s > 0; s >>= 1) {
        if (threadIdx.x < s) {
            sp[threadIdx.x] += sp[threadIdx.x + s];
            sn[threadIdx.x] += sn[threadIdx.x + s];
        }
        __syncthreads();
    }
    if (threadIdx.x == 0) { out[0] = sp[0]; out[1] = sn[0]; }
}

extern "C" void kernel_launch(void* const* d_in, const int* in_sizes, int n_in,
                              void* d_out, int out_size, void* d_ws, size_t ws_size,
                              hipStream_t stream) {
    const int*   data       = (const int*)  d_in[0];
    const float* global_W   = (const float*)d_in[1];
    const float* sense_W    = (const float*)d_in[2];
    const float* ctx_weight = (const float*)d_in[3];
    // d_in[4] = window (5), d_in[5] = negative (5) — fixed, baked into constants.

    const int B = in_sizes[0] / COLS;     // 131072
    float* partials = (float*)d_ws;       // 2*NBLOCKS floats = 16 KB
    float* out      = (float*)d_out;      // {pos_loss, neg_loss}

    sg_loss_kernel<<<NBLOCKS, THREADS, 0, stream>>>(
        data, global_W, sense_W, ctx_weight, B, partials);
    reduce_kernel<<<1, 256, 0, stream>>>(partials, NBLOCKS, out);
}